// Round 1
// baseline (1567.177 us; speedup 1.0000x reference)
//
#include <hip/hip_runtime.h>

#define N_NODES 100000
#define N_EDGES 3200000
#define HD      32
#define NLAYERS 4
#define NGRAPHS 1000
#define BN_EPS  1e-5f
#define NB_SCAN 98            // ceil(100001/1024) blocks cover i=0..N inclusive

// ---------------- encoder: h = x*W_enc + b_enc  (+ zero-init of ws buffers) ----
__global__ __launch_bounds__(256) void k_encoder(
    const float* __restrict__ x, const float* __restrict__ W_enc,
    const float* __restrict__ b_enc, float* __restrict__ h,
    float* __restrict__ stats, float* __restrict__ pooled, int* __restrict__ deg)
{
    int gid = blockIdx.x * 256 + threadIdx.x;
    if (gid < NLAYERS * 64)   stats[gid]  = 0.f;   // per-layer sum/sumsq buffers
    if (gid < NGRAPHS * HD)   pooled[gid] = 0.f;
    if (gid < N_NODES)        deg[gid]    = 0;
    if (gid < N_NODES * HD) {
        int i = gid >> 5, c = gid & 31;
        h[gid] = x[i] * W_enc[c] + b_enc[c];
    }
}

// ---------------- CSR build: histogram, scan, fill -----------------------------
__global__ __launch_bounds__(256) void k_hist(const int* __restrict__ ei,
                                              int* __restrict__ deg)
{
    int e = blockIdx.x * 256 + threadIdx.x;
    if (e < N_EDGES) atomicAdd(&deg[ei[N_EDGES + e]], 1);   // dst = ei[1][e]
}

__global__ __launch_bounds__(256) void k_scanA(const int* __restrict__ deg,
                                               int* __restrict__ bsums)
{
    __shared__ int red[256];
    int tid = threadIdx.x;
    int base = blockIdx.x * 1024 + tid * 4;
    int s = 0;
    #pragma unroll
    for (int k = 0; k < 4; ++k) { int i = base + k; s += (i < N_NODES) ? deg[i] : 0; }
    red[tid] = s; __syncthreads();
    for (int st = 128; st > 0; st >>= 1) {
        if (tid < st) red[tid] += red[tid + st];
        __syncthreads();
    }
    if (tid == 0) bsums[blockIdx.x] = red[0];
}

__global__ void k_scanB(const int* __restrict__ bsums, int* __restrict__ boffs)
{
    if (threadIdx.x == 0) {
        int acc = 0;
        for (int i = 0; i < NB_SCAN; ++i) { boffs[i] = acc; acc += bsums[i]; }
    }
}

__global__ __launch_bounds__(256) void k_scanC(const int* __restrict__ deg,
                                               const int* __restrict__ boffs,
                                               int* __restrict__ off,
                                               int* __restrict__ wcur)
{
    __shared__ int incl[256];
    int tid = threadIdx.x;
    int base = blockIdx.x * 1024 + tid * 4;
    int v[4]; int s = 0;
    #pragma unroll
    for (int k = 0; k < 4; ++k) {
        int i = base + k;
        v[k] = (i < N_NODES) ? deg[i] : 0;
        s += v[k];
    }
    incl[tid] = s; __syncthreads();
    for (int st = 1; st < 256; st <<= 1) {          // Hillis-Steele inclusive scan
        int add = (tid >= st) ? incl[tid - st] : 0;
        __syncthreads();
        incl[tid] += add;
        __syncthreads();
    }
    int excl = incl[tid] - s + boffs[blockIdx.x];
    #pragma unroll
    for (int k = 0; k < 4; ++k) {
        int i = base + k;
        if (i < N_NODES)       { off[i] = excl; wcur[i] = excl; }
        else if (i == N_NODES) { off[i] = excl; }   // off[N] = E
        excl += v[k];
    }
}

__global__ __launch_bounds__(256) void k_fill(const int* __restrict__ ei,
                                              int* __restrict__ wcur,
                                              int* __restrict__ csr)
{
    int e = blockIdx.x * 256 + threadIdx.x;
    if (e < N_EDGES) {
        int d = ei[N_EDGES + e];
        int pos = atomicAdd(&wcur[d], 1);
        csr[pos] = ei[e];                            // store src
    }
}

// ---------------- fused layer: CSR pull + (1+eps)h + MLP, stats accumulation ---
__global__ __launch_bounds__(256) void k_layer(
    const float* __restrict__ h, const int* __restrict__ off,
    const int* __restrict__ csr, const float* __restrict__ epsArr,
    const float* __restrict__ W1, const float* __restrict__ b1,
    const float* __restrict__ W2, const float* __restrict__ b2,
    float* __restrict__ z2out, float* __restrict__ stats, int layer)
{
    __shared__ float W1s[1024], W2s[1024], b1s[32], b2s[32];
    __shared__ float z1s[256], ts[256], red[512];
    int tid = threadIdx.x;
    const float* W1l = W1 + layer * 1024;
    const float* W2l = W2 + layer * 1024;
    for (int k = tid; k < 1024; k += 256) { W1s[k] = W1l[k]; W2s[k] = W2l[k]; }
    if (tid < 32) { b1s[tid] = b1[layer * 32 + tid]; b2s[tid] = b2[layer * 32 + tid]; }
    float onePlusEps = 1.0f + epsArr[layer];
    __syncthreads();

    int slot = tid >> 5, c = tid & 31, sbase = slot * 32;
    const int NG = (N_NODES + 7) / 8;   // 12500 groups of 8 nodes
    float lsum = 0.f, lsq = 0.f;

    for (int g = blockIdx.x; g < NG; g += gridDim.x) {
        int node = g * 8 + slot;
        float z1 = 0.f;
        if (node < N_NODES) {
            int j = off[node], jend = off[node + 1];
            float acc = 0.f;
            int sNext = (j < jend) ? csr[j] : 0;     // prefetch index
            while (j < jend) {
                int s = sNext;
                ++j;
                sNext = (j < jend) ? csr[j] : 0;
                acc += h[s * HD + c];                // 128B coalesced row gather
            }
            z1 = onePlusEps * h[node * HD + c] + acc;
        }
        z1s[tid] = z1;
        __syncthreads();

        float t = b1s[c];
        #pragma unroll
        for (int k = 0; k < 32; ++k) t = fmaf(z1s[sbase + k], W1s[k * 32 + c], t);
        t = fmaxf(t, 0.f);
        ts[tid] = t;
        __syncthreads();

        float z2 = b2s[c];
        #pragma unroll
        for (int k = 0; k < 32; ++k) z2 = fmaf(ts[sbase + k], W2s[k * 32 + c], z2);

        if (node < N_NODES) {
            z2out[node * HD + c] = z2;
            lsum += z2; lsq += z2 * z2;
        }
        __syncthreads();                             // before z1s/ts reuse
    }

    red[tid] = lsum; red[256 + tid] = lsq;
    __syncthreads();
    if (tid < 64) {
        int cc = tid & 31;
        int rb = (tid < 32) ? 0 : 256;
        float s = 0.f;
        #pragma unroll
        for (int nl = 0; nl < 8; ++nl) s += red[rb + nl * 32 + cc];
        atomicAdd(&stats[layer * 64 + tid], s);      // [0..31]=sum, [32..63]=sumsq
    }
}

// ---------------- BatchNorm (batch stats) + ReLU -> h --------------------------
__global__ __launch_bounds__(256) void k_bnapply(
    const float* __restrict__ z2, const float* __restrict__ stats,
    const float* __restrict__ gamma, const float* __restrict__ beta,
    float* __restrict__ h, int layer)
{
    int gid = blockIdx.x * 256 + threadIdx.x;
    if (gid >= N_NODES * HD) return;
    int c = gid & 31;
    const float invN = 1.0f / (float)N_NODES;
    float mu  = stats[layer * 64 + c] * invN;
    float var = stats[layer * 64 + 32 + c] * invN - mu * mu;
    float scale = gamma[layer * 32 + c] * rsqrtf(var + BN_EPS);
    float shift = beta[layer * 32 + c] - mu * scale;
    h[gid] = fmaxf(fmaf(z2[gid], scale, shift), 0.f);
}

// ---------------- global_add_pool (batch is sorted -> run-length reduce) -------
__global__ __launch_bounds__(256) void k_pool(const float* __restrict__ h,
                                              const int* __restrict__ batch,
                                              float* __restrict__ pooled)
{
    int c = threadIdx.x & 31, slot = threadIdx.x >> 5;
    int start = blockIdx.x * 256 + slot * 32;        // 32 consecutive nodes per slot
    if (start >= N_NODES) return;
    int end = min(start + 32, N_NODES);
    int cur = batch[start]; float acc = 0.f;
    for (int i = start; i < end; ++i) {
        int g = batch[i];
        if (g != cur) { atomicAdd(&pooled[cur * HD + c], acc); acc = 0.f; cur = g; }
        acc += h[i * HD + c];
    }
    atomicAdd(&pooled[cur * HD + c], acc);
}

// ---------------- classifier ---------------------------------------------------
__global__ __launch_bounds__(256) void k_cls(const float* __restrict__ pooled,
                                             const float* __restrict__ Wc,
                                             const float* __restrict__ bc,
                                             float* __restrict__ out)
{
    int gid = blockIdx.x * 256 + threadIdx.x;
    if (gid >= NGRAPHS * 2) return;
    int g = gid >> 1, c = gid & 1;
    float s = bc[c];
    #pragma unroll
    for (int k = 0; k < 32; ++k) s = fmaf(pooled[g * 32 + k], Wc[k * 2 + c], s);
    out[gid] = s;
}

extern "C" void kernel_launch(void* const* d_in, const int* in_sizes, int n_in,
                              void* d_out, int out_size, void* d_ws, size_t ws_size,
                              hipStream_t stream)
{
    const float* x      = (const float*)d_in[0];
    const int*   ei     = (const int*)d_in[1];    // [2, E] int
    const int*   batch  = (const int*)d_in[2];    // [N] int, sorted
    const float* W_enc  = (const float*)d_in[3];
    const float* b_enc  = (const float*)d_in[4];
    const float* epsArr = (const float*)d_in[5];
    const float* W1     = (const float*)d_in[6];
    const float* b1     = (const float*)d_in[7];
    const float* W2     = (const float*)d_in[8];
    const float* b2     = (const float*)d_in[9];
    const float* gamma  = (const float*)d_in[10];
    const float* beta   = (const float*)d_in[11];
    const float* Wc     = (const float*)d_in[12];
    const float* bc     = (const float*)d_in[13];
    float* out = (float*)d_out;

    char* ws = (char*)d_ws;
    size_t o = 0;
    auto alloc = [&](size_t bytes) {
        char* p = ws + o;
        o += (bytes + 255) & ~(size_t)255;
        return p;
    };
    float* h      = (float*)alloc((size_t)N_NODES * HD * 4);   // 12.8 MB
    float* z2     = (float*)alloc((size_t)N_NODES * HD * 4);   // 12.8 MB
    int*   csr    = (int*)  alloc((size_t)N_EDGES * 4);        // 12.8 MB
    int*   deg    = (int*)  alloc((size_t)N_NODES * 4);
    int*   offA   = (int*)  alloc((size_t)(N_NODES + 1) * 4);
    int*   wcur   = (int*)  alloc((size_t)N_NODES * 4);
    int*   bsums  = (int*)  alloc(512);
    int*   boffs  = (int*)  alloc(512);
    float* stats  = (float*)alloc(NLAYERS * 64 * 4);
    float* pooled = (float*)alloc((size_t)NGRAPHS * HD * 4);

    // encoder + zero-init (stats/pooled/deg)
    k_encoder<<<(N_NODES * HD + 255) / 256, 256, 0, stream>>>(x, W_enc, b_enc, h,
                                                              stats, pooled, deg);
    // CSR build (per call — ws is re-poisoned between launches)
    k_hist <<<(N_EDGES + 255) / 256, 256, 0, stream>>>(ei, deg);
    k_scanA<<<NB_SCAN, 256, 0, stream>>>(deg, bsums);
    k_scanB<<<1, 64, 0, stream>>>(bsums, boffs);
    k_scanC<<<NB_SCAN, 256, 0, stream>>>(deg, boffs, offA, wcur);
    k_fill <<<(N_EDGES + 255) / 256, 256, 0, stream>>>(ei, wcur, csr);

    for (int l = 0; l < NLAYERS; ++l) {
        k_layer  <<<1280, 256, 0, stream>>>(h, offA, csr, epsArr, W1, b1, W2, b2,
                                            z2, stats, l);
        k_bnapply<<<(N_NODES * HD + 255) / 256, 256, 0, stream>>>(z2, stats, gamma,
                                                                  beta, h, l);
    }
    k_pool<<<(N_NODES + 255) / 256, 256, 0, stream>>>(h, batch, pooled);
    k_cls <<<8, 256, 0, stream>>>(pooled, Wc, bc, out);
}